// Round 1
// baseline (229.294 us; speedup 1.0000x reference)
//
#include <hip/hip_runtime.h>
#include <math.h>

// out[tok, d] = cos(dot(x[tok,:], W1) + b1) * cos(phi) * W2[d] + b2[d]
// D = 1024, tokens = B*S = 32768. Fully memory-bound: read x once, write out once.

#define EMBED_D 1024

__global__ __launch_bounds__(256) void ffq_kernel(
    const float* __restrict__ x,
    const float* __restrict__ W1,
    const float* __restrict__ b1,
    const float* __restrict__ phi,
    const float* __restrict__ W2,
    const float* __restrict__ b2,
    float* __restrict__ out)
{
    const int tok = blockIdx.x;
    const int t   = threadIdx.x;          // 0..255, each handles 4 contiguous floats

    // ---- dot(x[tok,:], W1) : each thread one float4 ----
    const float4* x4  = (const float4*)(x + (size_t)tok * EMBED_D);
    const float4* w14 = (const float4*)W1;
    float4 xv = x4[t];
    float4 wv = w14[t];
    float v = xv.x * wv.x + xv.y * wv.y + xv.z * wv.z + xv.w * wv.w;

    // wave(64)-level shuffle reduction
    #pragma unroll
    for (int off = 32; off > 0; off >>= 1)
        v += __shfl_down(v, off, 64);

    __shared__ float partial[4];
    __shared__ float qsh;
    if ((t & 63) == 0) partial[t >> 6] = v;
    __syncthreads();

    if (t == 0) {
        float theta = partial[0] + partial[1] + partial[2] + partial[3] + b1[0];
        qsh = cosf(theta) * cosf(phi[0]);
    }
    __syncthreads();
    const float q = qsh;

    // ---- out[tok, 4t..4t+3] = q * W2 + b2 ----
    const float4* w24 = (const float4*)W2;
    const float4* b24 = (const float4*)b2;
    float4 w2v = w24[t];
    float4 b2v = b24[t];
    float4 o;
    o.x = fmaf(q, w2v.x, b2v.x);
    o.y = fmaf(q, w2v.y, b2v.y);
    o.z = fmaf(q, w2v.z, b2v.z);
    o.w = fmaf(q, w2v.w, b2v.w);
    ((float4*)(out + (size_t)tok * EMBED_D))[t] = o;
}

extern "C" void kernel_launch(void* const* d_in, const int* in_sizes, int n_in,
                              void* d_out, int out_size, void* d_ws, size_t ws_size,
                              hipStream_t stream) {
    const float* x   = (const float*)d_in[0];
    const float* W1  = (const float*)d_in[1];
    const float* b1  = (const float*)d_in[2];
    const float* phi = (const float*)d_in[3];
    const float* W2  = (const float*)d_in[4];
    const float* b2  = (const float*)d_in[5];
    float* out = (float*)d_out;

    const int ntok = in_sizes[0] / EMBED_D;   // B*S = 32768
    ffq_kernel<<<ntok, 256, 0, stream>>>(x, W1, b1, phi, W2, b2, out);
}